// Round 9
// baseline (158.537 us; speedup 1.0000x reference)
//
#include <hip/hip_runtime.h>
#include <hip/hip_bf16.h>
#include <math.h>

// Problem constants
#define Bb   4
#define Cc   128
#define Nn   4096          // 64*64 spatial
#define BN   (Bb * Nn)
#define HP   0.1f
#define EPSN 1e-10f
#define EPSM 0.001f

typedef __attribute__((ext_vector_type(8))) short short8;  // 8 bf16 = 4 VGPRs
typedef __attribute__((ext_vector_type(4))) float f32x4;   // MFMA accumulator

// Workspace layout (float offsets)
#define OFF_MEAN 0                 // [B*C]     = 512    (atomicAdd -> zeroed)
#define OFF_ACC  512               // [B]       = 4      (atomicAdd -> zeroed)
#define OFF_CTV  1024              // [B*N*2]   = 32768  (fully overwritten)
#define OFF_PMAX 33792             // [32][B*N] = 524288 (fully overwritten)
#define OFF_SSP  558080            // [32][B*N] = 524288 (fully overwritten)
#define OFF_FXN  1082368           // bf16 packed [B*N*C] = 1048576 floats
#define OFF_FYN  2130944           // bf16 packed [B*N*C]

// Packed fragment-major layout (per batch, element index):
//   pk(n,k) = (n>>4)*2048 + (k>>3)*128 + (n&15)*8 + (k&7)
// -> an MFMA A/B fragment load (16 rows x 8 ch for the wave's (i|j,kt)) is a
//    single lane-linear 1 KB global_load_dwordx4: lane(q,l15) offset =
//    (q*16+l15)*16 B. No gather, no LDS staging needed in the GEMM.

__device__ __forceinline__ ushort f2bf(float v)
{
    __hip_bfloat16 h = __float2bfloat16(v);
    return *(ushort*)&h;
}

// ---------------------------------------------------------------------------
// Kernel 1: per-(b,c) sums of feature_y over spatial dim (atomicAdd partials)
__global__ void k_mean(const float* __restrict__ fy, float* __restrict__ mean)
{
    int b = blockIdx.x >> 5;
    int chunk = blockIdx.x & 31;
    int c = threadIdx.x;           // 128 threads, one per channel
    const float* p = fy + ((size_t)b * Nn + (size_t)chunk * 128) * Cc + c;
    float s = 0.f;
    for (int n = 0; n < 128; ++n) s += p[(size_t)n * Cc];
    atomicAdd(&mean[b * Cc + c], s);
}

// ---------------------------------------------------------------------------
// Kernel 2: center by spatial mean of y, L2-normalize over C, emit bf16 in
// PACKED layout. Block = 16 rows (one packed group); thread t: row r = t>>4,
// channel-chunk c = t&15 (8 channels). Row reduction = 16-lane xor-shuffles.
__global__ void k_norm(const float* __restrict__ fx, const float* __restrict__ fy,
                       const float* __restrict__ mean,
                       ushort* __restrict__ fxn, ushort* __restrict__ fyn)
{
    const int bn0 = blockIdx.x * 16;         // first row of the group
    const int b = bn0 >> 12;
    const int t = threadIdx.x;
    const int r = t >> 4, c = t & 15;
    const int row = bn0 + r;

    const float* px = fx + (size_t)row * Cc + c * 8;
    const float* py = fy + (size_t)row * Cc + c * 8;
    const float* pm = mean + b * Cc + c * 8;

    float xv[8], yv[8];
    float sx = 0.f, sy = 0.f;
    #pragma unroll
    for (int e = 0; e < 8; ++e) {
        float m = pm[e] * (1.f / Nn);
        float x = px[e] - m;
        float y = py[e] - m;
        xv[e] = x; yv[e] = y;
        sx += x * x; sy += y * y;
    }
    #pragma unroll
    for (int o = 1; o < 16; o <<= 1) {
        sx += __shfl_xor(sx, o);
        sy += __shfl_xor(sy, o);
    }
    float ix = 1.f / (sqrtf(sx) + EPSN);
    float iy = 1.f / (sqrtf(sy) + EPSN);

    // Packed dest: b*N*C + ((bn0 & 4095)>>4)*2048 + c*128 + r*8
    size_t dst = (size_t)b * Nn * Cc
               + (size_t)((bn0 & (Nn - 1)) >> 4) * 2048 + c * 128 + r * 8;
    ushort ox[8], oy[8];
    #pragma unroll
    for (int e = 0; e < 8; ++e) {
        ox[e] = f2bf(xv[e] * ix);
        oy[e] = f2bf(yv[e] * iy);
    }
    *(short8*)&fxn[dst] = *(short8*)ox;
    *(short8*)&fyn[dst] = *(short8*)oy;
}

// ---------------------------------------------------------------------------
// MFMA core: per batch, S = X · Y^T  (M=N=4096, K=C=128). ZERO-LDS GEMM:
// block (bx,my,b) = one 128x128 tile, 2x2 waves of 64x64; all A/B fragments
// are lane-linear 1 KB loads from the packed global layout (L2-resident,
// 2 MB/batch). Only LDS: 1 KB sred for combining the wx wave pair.
// acc born+dies inside the block body -> AGPRs (r2/r7/r8 no-spill rule).
// PASS 1: per-row max of dot -> pmax[my][b*N+row]
// PASS 2: per-row sum exp(fma(dot,c1,c0)) -> ssp[my][b*N+row], coeffs from ctv.
template <int PASS>
__global__ __launch_bounds__(256, 2) void k_gemm(
    const ushort* __restrict__ fxn, const ushort* __restrict__ fyn,
    float* __restrict__ pmax, const float* __restrict__ ctv,
    float* __restrict__ ssp)
{
    __shared__ float sred[256];            // [row128][wx]

    const int tid  = threadIdx.x;
    const int lane = tid & 63;
    const int w    = tid >> 6;
    const int wy = w >> 1, wx = w & 1;     // wave's 64x64 quadrant
    const int l15 = lane & 15, q = lane >> 4;
    const int n0 = blockIdx.x * 128;
    const int my = blockIdx.y;             // m-tile 0..31
    const int m0 = my * 128;
    const int b  = blockIdx.z;

    const ushort* pA = fxn + (size_t)b * Nn * Cc
                     + (size_t)((n0 + wy * 64) >> 4) * 2048 + q * 128 + l15 * 8;
    const ushort* pB = fyn + (size_t)b * Nn * Cc
                     + (size_t)((m0 + wx * 64) >> 4) * 2048 + q * 128 + l15 * 8;

    f32x4 acc[4][4];
    #pragma unroll
    for (int i = 0; i < 4; ++i)
        #pragma unroll
        for (int j = 0; j < 4; ++j)
            acc[i][j] = (f32x4){0.f, 0.f, 0.f, 0.f};

    #pragma unroll
    for (int kt = 0; kt < 4; ++kt) {
        short8 a[4], bb[4];
        #pragma unroll
        for (int i = 0; i < 4; ++i)
            a[i] = *(const short8*)(pA + i * 2048 + kt * 512);
        #pragma unroll
        for (int j = 0; j < 4; ++j)
            bb[j] = *(const short8*)(pB + j * 2048 + kt * 512);
        #pragma unroll
        for (int i = 0; i < 4; ++i)
            #pragma unroll
            for (int j = 0; j < 4; ++j)
                acc[i][j] = __builtin_amdgcn_mfma_f32_16x16x32_bf16(
                    a[i], bb[j], acc[i][j], 0, 0, 0);
    }

    // Epilogue. C/D layout: col = lane&15, row = (lane>>4)*4 + reg [m89].
    const float2* ctvp = (const float2*)ctv + (size_t)b * Nn + n0 + wy * 64;
    #pragma unroll
    for (int i = 0; i < 4; ++i)
        #pragma unroll
        for (int r = 0; r < 4; ++r) {
            float v;
            if (PASS == 1) {
                v = fmaxf(fmaxf(acc[i][0][r], acc[i][1][r]),
                          fmaxf(acc[i][2][r], acc[i][3][r]));
                #pragma unroll
                for (int o = 1; o < 16; o <<= 1) v = fmaxf(v, __shfl_xor(v, o));
            } else {
                float2 cc = ctvp[i * 16 + q * 4 + r];   // {c0, c1}, 16-lane bcast
                v = __expf(fmaf(acc[i][0][r], cc.y, cc.x))
                  + __expf(fmaf(acc[i][1][r], cc.y, cc.x))
                  + __expf(fmaf(acc[i][2][r], cc.y, cc.x))
                  + __expf(fmaf(acc[i][3][r], cc.y, cc.x));  // args <= ~0
                #pragma unroll
                for (int o = 1; o < 16; o <<= 1) v += __shfl_xor(v, o);
            }
            if (l15 == 0) sred[(wy * 64 + i * 16 + q * 4 + r) * 2 + wx] = v;
        }
    __syncthreads();
    if (tid < 128) {
        float v = (PASS == 1) ? fmaxf(sred[tid * 2], sred[tid * 2 + 1])
                              : (sred[tid * 2] + sred[tid * 2 + 1]);
        float* dst = (PASS == 1) ? pmax : ssp;
        dst[(size_t)my * BN + b * Nn + n0 + tid] = v;
    }
}

// ---------------------------------------------------------------------------
// Reduce 32 max partials -> affine exp coefficients {c0,c1} per row
//   d = 1 - maxdot; t = 1/(HP*(d+eps)); arg(dot) = dot*t + (d-1)*t
__global__ void k_dmin(const float* __restrict__ pmax, float* __restrict__ ctv)
{
    int i = blockIdx.x * 256 + threadIdx.x;   // 0 .. B*N-1
    float g = -1e30f;
    #pragma unroll
    for (int z = 0; z < 32; ++z) g = fmaxf(g, pmax[(size_t)z * BN + i]);
    float d = 1.f - g;
    float t = 1.f / (HP * (d + EPSM));
    ((float2*)ctv)[i] = (float2){(d - 1.f) * t, t};
}

// ---------------------------------------------------------------------------
// Stage 1 of final reduction: per-row 1/s, block-sum, atomicAdd per batch.
__global__ void k_partial(const float* __restrict__ ssp, float* __restrict__ acc)
{
    int i = blockIdx.x * 256 + threadIdx.x;   // 0 .. B*N-1 (block spans one batch)
    float t = 0.f;
    #pragma unroll
    for (int z = 0; z < 32; ++z) t += ssp[(size_t)z * BN + i];
    float s = 1.f / t;
    #pragma unroll
    for (int o = 32; o > 0; o >>= 1) s += __shfl_xor(s, o);
    __shared__ float red[4];
    if ((threadIdx.x & 63) == 0) red[threadIdx.x >> 6] = s;
    __syncthreads();
    if (threadIdx.x == 0)
        atomicAdd(&acc[i >> 12], red[0] + red[1] + red[2] + red[3]);
}

__global__ void k_out(const float* __restrict__ acc, float* __restrict__ out)
{
    int b = threadIdx.x;
    if (b < Bb) out[b] = -logf(acc[b] * (1.f / Nn));
}

// ---------------------------------------------------------------------------
extern "C" void kernel_launch(void* const* d_in, const int* in_sizes, int n_in,
                              void* d_out, int out_size, void* d_ws, size_t ws_size,
                              hipStream_t stream)
{
    const float* fx = (const float*)d_in[0];
    const float* fy = (const float*)d_in[1];
    float* out = (float*)d_out;
    float* ws  = (float*)d_ws;

    float* mean = ws + OFF_MEAN;
    float* acc  = ws + OFF_ACC;
    float* ctv  = ws + OFF_CTV;
    float* pmax = ws + OFF_PMAX;
    float* ssp  = ws + OFF_SSP;
    ushort* fxn = (ushort*)(ws + OFF_FXN);
    ushort* fyn = (ushort*)(ws + OFF_FYN);

    // zero the atomicAdd accumulators (mean @0..511, acc @512..515)
    hipMemsetAsync(ws, 0, 516 * sizeof(float), stream);

    k_mean<<<dim3(Bb * 32), dim3(128), 0, stream>>>(fy, mean);
    k_norm<<<dim3(BN / 16), dim3(256), 0, stream>>>(fx, fy, mean, fxn, fyn);

    dim3 gg(32, 32, Bb);   // 4096 blocks, one 128x128 tile each, zero-LDS
    k_gemm<1><<<gg, dim3(256), 0, stream>>>(fxn, fyn, pmax, nullptr, nullptr);
    k_dmin<<<dim3(BN / 256), dim3(256), 0, stream>>>(pmax, ctv);
    k_gemm<2><<<gg, dim3(256), 0, stream>>>(fxn, fyn, nullptr, ctv, ssp);
    k_partial<<<dim3(BN / 256), dim3(256), 0, stream>>>(ssp, acc);
    k_out<<<dim3(1), dim3(64), 0, stream>>>(acc, out);
}